// Round 1
// baseline (12199.711 us; speedup 1.0000x reference)
//
#include <hip/hip_runtime.h>

// LearnableCell: FiLM'd LayerNorm-GRU, fused single kernel.
// B=32 chains -> 32 workgroups; serial T=8192 loop inside the kernel.
// Thread g owns gate-row g: Wh[g,:] (128 f32) + Wx[g,:] (16 f32) in VGPRs.
// h lives in LDS; per step: matvec -> joint LN block-reduce -> FiLM ->
// gates (threads j<128) -> h update + store.

#define T_STEPS 8192
#define BATCH   32
#define HDIM    128
#define GDIM    384
#define IDIM    16
#define LN_EPS  1e-5f

typedef float f32x4 __attribute__((ext_vector_type(4)));

// Barrier that waits LDS only (no vmcnt drain: stores / x-prefetch stay in flight).
__device__ __forceinline__ void block_barrier() {
  asm volatile("s_waitcnt lgkmcnt(0)\n\ts_barrier" ::: "memory");
}

__device__ __forceinline__ float fast_sigmoid(float x) {
  return 1.f / (1.f + __expf(-x));
}
__device__ __forceinline__ float fast_tanh(float x) {
  // tanh(x) = 1 - 2/(e^(2x)+1); saturates correctly at +/-inf.
  float e2 = __expf(2.f * x);
  return 1.f - 2.f / (e2 + 1.f);
}

__global__ __launch_bounds__(GDIM, 1) void gru_fused(
    const float* __restrict__ xs,       // [B,T,I]
    const float* __restrict__ state,    // [1,B,H]
    const float* __restrict__ alpha_i,  // [B,G]
    const float* __restrict__ beta_i,   // [B,G]
    const float* __restrict__ alpha_h,  // [B,G]
    const float* __restrict__ beta_h,   // [B,G]
    const float* __restrict__ Wx,       // [G,I]
    const float* __restrict__ bx,       // [G]
    const float* __restrict__ Wh,       // [G,H]
    const float* __restrict__ bh,       // [G]
    float* __restrict__ out)            // [B,T,H] then [B,1,H]
{
  __shared__ float lds_h[HDIM];
  __shared__ float lds_hh[GDIM];
  __shared__ float lds_ih[GDIM];
  __shared__ float lds_x[2][IDIM];
  __shared__ f32x4 lds_red[GDIM / 64];

  const int b    = blockIdx.x;
  const int g    = threadIdx.x;
  const int wid  = g >> 6;
  const int lane = g & 63;

  // ---- per-thread persistent weights (registers) ----
  f32x4 wh4[HDIM / 4];
#pragma unroll
  for (int i = 0; i < HDIM / 4; ++i)
    wh4[i] = ((const f32x4*)(Wh + (size_t)g * HDIM))[i];
  f32x4 wx4[IDIM / 4];
#pragma unroll
  for (int i = 0; i < IDIM / 4; ++i)
    wx4[i] = ((const f32x4*)(Wx + (size_t)g * IDIM))[i];

  const float bxg  = bx[g];
  const float bhg  = bh[g];
  const float aig  = alpha_i[b * GDIM + g];
  const float big  = beta_i[b * GDIM + g];
  const float ahg  = alpha_h[b * GDIM + g];
  const float bhg2 = beta_h[b * GDIM + g];

  const float* xs_b = xs + (size_t)b * T_STEPS * IDIM;

  if (g < HDIM) lds_h[g] = state[b * HDIM + g];
  if (g < IDIM) lds_x[0][g] = xs_b[g];
  // prefetch x[t=1]; steady-state distance-2 prefetch below
  float xpre = (g < IDIM) ? xs_b[IDIM + g] : 0.f;
  block_barrier();

  float* out_b = out + (size_t)b * T_STEPS * HDIM;

  for (int t = 0; t < T_STEPS; ++t) {
    // ---- input projection matvec (16 MACs) ----
    const f32x4* xb = (const f32x4*)lds_x[t & 1];
    f32x4 aI = {0.f, 0.f, 0.f, 0.f};
#pragma unroll
    for (int i = 0; i < IDIM / 4; ++i)
      aI = __builtin_elementwise_fma(wx4[i], xb[i], aI);
    float accI = bxg + ((aI.x + aI.y) + (aI.z + aI.w));

    // ---- recurrent matvec (128 MACs, h broadcast from LDS) ----
    const f32x4* hb = (const f32x4*)lds_h;
    f32x4 aH0 = {0.f, 0.f, 0.f, 0.f};
    f32x4 aH1 = {0.f, 0.f, 0.f, 0.f};
#pragma unroll
    for (int i = 0; i < HDIM / 4; i += 2) {
      aH0 = __builtin_elementwise_fma(wh4[i],     hb[i],     aH0);
      aH1 = __builtin_elementwise_fma(wh4[i + 1], hb[i + 1], aH1);
    }
    f32x4 aH = aH0 + aH1;
    float accH = bhg + ((aH.x + aH.y) + (aH.z + aH.w));

    // ---- joint block reduction: sum & sumsq for both LNs ----
    f32x4 red = { accI, accI * accI, accH, accH * accH };
#pragma unroll
    for (int m = 32; m >= 1; m >>= 1) {
      f32x4 o;
      o.x = __shfl_xor(red.x, m);
      o.y = __shfl_xor(red.y, m);
      o.z = __shfl_xor(red.z, m);
      o.w = __shfl_xor(red.w, m);
      red += o;
    }
    if (lane == 0) lds_red[wid] = red;
    block_barrier();
    f32x4 s = lds_red[0];
#pragma unroll
    for (int w = 1; w < GDIM / 64; ++w) s += lds_red[w];

    const float inv = 1.f / (float)GDIM;
    float mI = s.x * inv;
    float vI = s.y * inv - mI * mI;
    float rI = rsqrtf(vI + LN_EPS);
    float mH = s.z * inv;
    float vH = s.w * inv - mH * mH;
    float rH = rsqrtf(vH + LN_EPS);

    float ihg = (accI - mI) * rI * aig + big;
    float hhg = (accH - mH) * rH * ahg + bhg2;
    lds_ih[g] = ihg;
    lds_hh[g] = hhg;
    block_barrier();

    // ---- x prefetch pipeline: publish x[t+1], fetch x[t+2] ----
    if (g < IDIM) {
      lds_x[(t + 1) & 1][g] = xpre;
      int tn = (t + 2 < T_STEPS) ? (t + 2) : t;
      xpre = xs_b[(size_t)tn * IDIM + g];
    }

    // ---- gates + h update (threads j < 128) ----
    if (g < HDIM) {
      float hr  = lds_hh[g];
      float hi  = lds_hh[g + HDIM];
      float hn  = lds_hh[g + 2 * HDIM];
      float ir  = lds_ih[g];
      float ii  = lds_ih[g + HDIM];
      float in_ = lds_ih[g + 2 * HDIM];

      float resetg = fast_sigmoid(ir + hr);
      float inputg = fast_sigmoid(ii + hi);
      float newg   = fast_tanh(in_ + resetg * hn);
      float hold   = lds_h[g];
      float hy     = newg + inputg * (hold - newg);

      lds_h[g] = hy;
      out_b[(size_t)t * HDIM + g] = hy;  // fire-and-forget store
    }
    block_barrier();
  }

  if (g < HDIM)
    out[(size_t)BATCH * T_STEPS * HDIM + b * HDIM + g] = lds_h[g];
}

extern "C" void kernel_launch(void* const* d_in, const int* in_sizes, int n_in,
                              void* d_out, int out_size, void* d_ws, size_t ws_size,
                              hipStream_t stream) {
  const float* xs      = (const float*)d_in[0];
  const float* state   = (const float*)d_in[1];
  const float* alpha_i = (const float*)d_in[2];
  const float* beta_i  = (const float*)d_in[3];
  const float* alpha_h = (const float*)d_in[4];
  const float* beta_h  = (const float*)d_in[5];
  const float* Wx      = (const float*)d_in[6];
  const float* bx      = (const float*)d_in[7];
  const float* Wh      = (const float*)d_in[8];
  const float* bh      = (const float*)d_in[9];
  float* out = (float*)d_out;

  gru_fused<<<dim3(BATCH), dim3(GDIM), 0, stream>>>(
      xs, state, alpha_i, beta_i, alpha_h, beta_h, Wx, bx, Wh, bh, out);
}